// Round 3
// baseline (212.749 us; speedup 1.0000x reference)
//
#include <hip/hip_runtime.h>
#include <math.h>

// Round 9: single-wave pipeline, ZERO barriers.
// Round 8 measured VALUBusy=65% with ~55% of cycles not issuing: the 2-wave
// producer/consumer structure pays max(wave0,wave1) + a barrier drain every
// 4 steps. One 64-lane wave can run the whole step pipeline itself:
//   lin+decoder(step i)  ||  conv-LUT(step i+1)  ||  encoder(step i+2)
// software-pipelined through double-buffered s_bits / s_p. A single wave's
// DS pipe is in-order, so every LDS handoff (bits -> conv, p -> lin,
// s_part write -> read) is race-free with no __syncthreads at all.
// Grid = B blocks of 64 threads (8 waves/CU, 2/SIMD); each loop iteration
// carries 3 independent pipeline stages of ILP (all DS reads issued at the
// top, consumed ~40 instructions later).
// s_p chunks padded to 20 floats so each lin lane's 18-float read is
// 16B-aligned (4x ds_read_b128 + 1x b64, 4 distinct addrs -> broadcast).
// Encoder / conv-LUT sums / lin fma chain / decoder FP ops are byte-identical
// to round 8. No T%4 requirement.

typedef float v2f __attribute__((ext_vector_type(2)));

__global__ __launch_bounds__(64, 2) void snn_step_kernel(
    const float* __restrict__ x,       // [B,1,15,15]
    const float* __restrict__ conv_w,  // [2,1,4,4]
    const float* __restrict__ conv_b,  // [2]
    const float* __restrict__ lin_w,   // [10,72]
    const float* __restrict__ lin_b,   // [10]
    float* __restrict__ out,           // spk_out[B,10] ++ mem_rec[T,B,10] ++ spk_rec[T,B,10]
    int T, int B)
{
    const int b = blockIdx.x;
    const int w = threadIdx.x;   // single wave: lane id

    __shared__ float  s_linw[720];
    __shared__ float  s_linb[10];
    __shared__ float4 s_lut[4][32];        // [ky][5-bit row bits] -> 4 partial sums
    __shared__ unsigned int s_bits[2][16]; // double-buffered packed spike rows
    __shared__ float  s_p[2][80];          // padded: 4 chunks x 20 floats
    __shared__ float  s_part[64];

    // ---- staging: lin weights + conv LUT (64 threads) ----
    for (int j = w; j < 720; j += 64) s_linw[j] = lin_w[j];
    if (w < 10) s_linb[w] = lin_b[w];
#pragma unroll
    for (int e = 0; e < 2; ++e) {
        const int t  = w + 64 * e;
        const int ky = t >> 5, n = t & 31;
        float s00 = 0.f, s01 = 0.f, s10 = 0.f, s11 = 0.f;
#pragma unroll
        for (int kx = 0; kx < 4; ++kx) {
            const float w0 = conv_w[ky * 4 + kx];        // ch0
            const float w1 = conv_w[16 + ky * 4 + kx];   // ch1
            if ((n >> kx) & 1)       { s00 += w0; s01 += w1; }  // dx = 0
            if ((n >> (kx + 1)) & 1) { s10 += w0; s11 += w1; }  // dx = 1
        }
        s_lut[ky][n] = make_float4(s00, s01, s10, s11);
    }
    __syncthreads();   // trivial: one wave; only orders staging vs use

    // ===== encoder state: lane w owns pixel (row = 4k + (w>>4), col = w&15) =====
    const int jrow = w >> 4, col = w & 15;
    float ve[4], cur[4];
#pragma unroll
    for (int k = 0; k < 4; ++k) {
        const int  row = 4 * k + jrow;
        const bool act = (col < 15) && (row < 15);
        ve[k]  = 0.f;
        cur[k] = act ? __fmul_rn(x[(size_t)b * 225 + row * 15 + col], 10.0f) : 0.f;
    }

    // ===== conv lane params =====
    const bool convlane = (w < 36);
    const int py = w / 6, px = w - 6 * py;   // pooled output coords
    const int wordsel = py;                  // words py..py+2 hold rows 2py..2py+5
    const int shx = 2 * px, shx16 = shx + 16;
    const int off0 = (w < 18) ? w : (w + 2); // padded-chunk offset for p[w]; +40 for p[36+w]
    const v2f cb2 = (v2f){conv_b[0], conv_b[1]};

    // ===== lin/decoder lane params =====
    const int lo = w >> 2, lq = w & 3;
    float lwreg[18];
#pragma unroll
    for (int jj = 0; jj < 18; ++jj) {
        int idx = lo * 72 + lq * 18 + jj;
        lwreg[jj] = s_linw[idx < 720 ? idx : 719];   // clamp for lanes >= 40
    }
    const float lbias = (w < 10) ? s_linb[w] : 0.f;
    float v = 0.f, i_syn = 0.f, sc = 0.f;
    const size_t BO = (size_t)B * 10;
    float* mp  = out + BO + (size_t)b * 10 + w;
    float* spp = out + BO + (size_t)T * BO + (size_t)b * 10 + w;

    // encoder step for all 64 lanes + ballot bit-pack -> s_bits[bufsel]
    auto enc_pack = [&](int bufsel) {
        unsigned long long bal0, bal1, bal2, bal3;
        {
            float vn = __fadd_rn(ve[0], __fmul_rn(0.1f, __fsub_rn(cur[0], ve[0])));
            bool  sp = (vn > 1.0f);
            ve[0] = sp ? 0.f : vn;
            bal0  = __ballot(sp);
        }
        {
            float vn = __fadd_rn(ve[1], __fmul_rn(0.1f, __fsub_rn(cur[1], ve[1])));
            bool  sp = (vn > 1.0f);
            ve[1] = sp ? 0.f : vn;
            bal1  = __ballot(sp);
        }
        {
            float vn = __fadd_rn(ve[2], __fmul_rn(0.1f, __fsub_rn(cur[2], ve[2])));
            bool  sp = (vn > 1.0f);
            ve[2] = sp ? 0.f : vn;
            bal2  = __ballot(sp);
        }
        {
            float vn = __fadd_rn(ve[3], __fmul_rn(0.1f, __fsub_rn(cur[3], ve[3])));
            bool  sp = (vn > 1.0f);
            ve[3] = sp ? 0.f : vn;
            bal3  = __ballot(sp);
        }
        // masks are wave-uniform; lanes 0..7 pick their 32-bit word
        unsigned long long m01 = (w & 2) ? bal1 : bal0;
        unsigned long long m23 = (w & 2) ? bal3 : bal2;
        unsigned long long m   = (w & 4) ? m23 : m01;
        unsigned word = (unsigned)((w & 1) ? (m >> 32) : m);
        if (w < 8) s_bits[bufsel][w] = word;
    };

    // conv LUT: 5-bit window rows -> pooled outputs -> s_p[dbuf] (padded layout)
    auto conv_lut = [&](unsigned wb0, unsigned wb1, unsigned wb2, int dbuf) {
        const int i0 = (wb0 >> shx)   & 31;
        const int i1 = (wb0 >> shx16) & 31;
        const int i2 = (wb1 >> shx)   & 31;
        const int i3 = (wb1 >> shx16) & 31;
        const int i4 = (wb2 >> shx)   & 31;

        const float4 f0 = s_lut[0][i0];
        const float4 f1 = s_lut[1][i1];
        const float4 f2 = s_lut[2][i2];
        const float4 f3 = s_lut[3][i3];
        const float4 g0 = s_lut[0][i1];
        const float4 g1 = s_lut[1][i2];
        const float4 g2 = s_lut[2][i3];
        const float4 g3 = s_lut[3][i4];

        v2f a00 = (v2f){f0.x, f0.y};  a00 += (v2f){f1.x, f1.y};
        a00 += (v2f){f2.x, f2.y};     a00 += (v2f){f3.x, f3.y};
        v2f a01 = (v2f){f0.z, f0.w};  a01 += (v2f){f1.z, f1.w};
        a01 += (v2f){f2.z, f2.w};     a01 += (v2f){f3.z, f3.w};
        v2f a10 = (v2f){g0.x, g0.y};  a10 += (v2f){g1.x, g1.y};
        a10 += (v2f){g2.x, g2.y};     a10 += (v2f){g3.x, g3.y};
        v2f a11 = (v2f){g0.z, g0.w};  a11 += (v2f){g1.z, g1.w};
        a11 += (v2f){g2.z, g2.w};     a11 += (v2f){g3.z, g3.w};

        v2f v00 = a00 + cb2, v01 = a01 + cb2;
        v2f v10 = a10 + cb2, v11 = a11 + cb2;
        v2f m2 = __builtin_elementwise_max(
                     __builtin_elementwise_max(v00, v01),
                     __builtin_elementwise_max(v10, v11));

        float* pbuf = s_p[dbuf];
        pbuf[off0]      = m2.x;   // p[w]      (chunk-padded)
        pbuf[off0 + 40] = m2.y;   // p[36 + w]
    };

    // ---- prologue: bits(0), bits(1), p(0) ----
    enc_pack(0);
    enc_pack(1);
    {
        unsigned wb0 = 0, wb1 = 0, wb2 = 0;
        if (convlane) {
            const unsigned* bb = &s_bits[0][wordsel];
            wb0 = bb[0]; wb1 = bb[1]; wb2 = bb[2];
        }
        if (convlane) conv_lut(wb0, wb1, wb2, 0);
    }

    // ---- main loop: lin(i) || conv(i+1) || enc(i+2), no barriers ----
    for (int i = 0; i < T; ++i) {
        const int pb = i & 1;    // lin reads s_p[pb]; enc writes s_bits[pb]
        const int cb = pb ^ 1;   // conv reads s_bits[cb], writes s_p[cb]

        // issue conv bit reads for step i+1 (consumed after enc)
        unsigned wb0 = 0, wb1 = 0, wb2 = 0;
        if (convlane) {
            const unsigned* bb = &s_bits[cb][wordsel];
            wb0 = bb[0]; wb1 = bb[1]; wb2 = bb[2];
        }

        // issue lin reads for step i (16B-aligned padded chunks)
        float pv[18];
        {
            const float* pp = &s_p[pb][lq * 20];
#pragma unroll
            for (int jj = 0; jj < 18; ++jj) pv[jj] = pp[jj];
        }

        // encoder for step i+2 (pure VALU, hides the DS reads above)
        enc_pack(pb);

        // conv for step i+1
        if (convlane) conv_lut(wb0, wb1, wb2, cb);

        // lin + decoder for step i
        float partial = 0.0f;
#pragma unroll
        for (int jj = 0; jj < 18; ++jj)
            partial = fmaf(lwreg[jj], pv[jj], partial);
        s_part[w] = partial;

        float vd  = __fadd_rn(v, __fmul_rn(0.1f, __fsub_rn(i_syn, v)));
        float id  = __fsub_rn(i_syn, __fmul_rn(0.2f, i_syn));
        float spk = (vd > 1.0f) ? 1.0f : 0.0f;
        v = (vd > 1.0f) ? 0.0f : vd;
        sc += spk;

        float4 pr = *(const float4*)&s_part[4 * (w < 10 ? w : 0)];
        float lin = __fadd_rn(__fadd_rn(__fadd_rn(__fadd_rn(pr.x, pr.y), pr.z), pr.w), lbias);
        i_syn = __fadd_rn(id, lin);

        if (w < 10) { *mp = v; *spp = spk; }
        mp  += BO;
        spp += BO;
    }

    if (w < 10) out[(size_t)b * 10 + w] = sc;
}

extern "C" void kernel_launch(void* const* d_in, const int* in_sizes, int n_in,
                              void* d_out, int out_size, void* d_ws, size_t ws_size,
                              hipStream_t stream) {
    const float* x      = (const float*)d_in[0];
    const float* conv_w = (const float*)d_in[1];
    const float* conv_b = (const float*)d_in[2];
    const float* lin_w  = (const float*)d_in[3];
    const float* lin_b  = (const float*)d_in[4];
    float* out = (float*)d_out;

    const int B = in_sizes[0] / 225;             // x is [B,1,15,15]
    const int T = (out_size / (B * 10) - 1) / 2; // out = B*10 * (1 + 2T); T=300

    snn_step_kernel<<<B, 64, 0, stream>>>(x, conv_w, conv_b, lin_w, lin_b, out, T, B);
}